// Round 1
// baseline (427.984 us; speedup 1.0000x reference)
//
#include <hip/hip_runtime.h>

#define BR 64
#define EC 131072

// Monotonic float->uint mapping (order-preserving, bijective)
__device__ __forceinline__ unsigned map_f(float f) {
    unsigned b = __float_as_uint(f);
    return (b & 0x80000000u) ? ~b : (b | 0x80000000u);
}
__device__ __forceinline__ float unmap_f(unsigned u) {
    unsigned b = (u & 0x80000000u) ? (u & 0x7FFFFFFFu) : ~u;
    return __uint_as_float(b);
}

// EXACT numpy-op-sequence value computation. contract(off) so every kernel
// computes bit-identical values (and matches numpy's per-op rounding).
__device__ __forceinline__ void compute_vals(float x, float bt, float gmax, float bp,
                                             float* nb, float* bo) {
#pragma clang fp contract(off)
    float q = x / gmax;
    float t = 1.0f - q;
    float p = t * bp;
    float nbv = bt + p;
    *nb = nbv;
    *bo = fmaxf(x, 0.0f) + nbv;
}

__device__ __forceinline__ unsigned umax_(unsigned a, unsigned b) { return a > b ? a : b; }

// ---------------- Kernel A: global max of x ----------------
__global__ void kmax(const float4* __restrict__ x4, unsigned* ws, int nvec) {
    unsigned m = 0;
    int stride = gridDim.x * blockDim.x;
    for (int v = blockIdx.x * blockDim.x + threadIdx.x; v < nvec; v += stride) {
        float4 xv = x4[v];
        m = umax_(m, map_f(xv.x)); m = umax_(m, map_f(xv.y));
        m = umax_(m, map_f(xv.z)); m = umax_(m, map_f(xv.w));
    }
    for (int off = 32; off; off >>= 1) m = umax_(m, __shfl_down(m, off, 64));
    __shared__ unsigned sm[16];
    int wid = threadIdx.x >> 6, lane = threadIdx.x & 63;
    if (lane == 0) sm[wid] = m;
    __syncthreads();
    if (threadIdx.x == 0) {
        unsigned mm = sm[0];
        int nw = blockDim.x >> 6;
        for (int w = 1; w < nw; ++w) mm = umax_(mm, sm[w]);
        atomicMax(ws, mm);
    }
}

// ---------------- Kernel B: per-row radix select (K-th largest) ----------------
// USE_NB=0: select on boosted, K=ceil(sp[1]*E). USE_NB=1: select on new_boost,
// K=ws[2] (to_activate), early-exit if 0.
template<int USE_NB>
__global__ __launch_bounds__(1024) void kselect(
        const float* __restrict__ x, const float* __restrict__ bt,
        const float* __restrict__ sp, const float* __restrict__ bp_p,
        unsigned* ws) {
    unsigned K;
    if (USE_NB) {
        K = ws[2];
        if (K == 0) return;
        if (K > EC) K = EC;
    } else {
        K = (unsigned)ceilf(sp[1] * (float)EC);
        if (K > EC) K = EC;
        if (K == 0) K = 1;
    }
    int row = blockIdx.x;
    float gmax = unmap_f(ws[0]);
    float bp = *bp_p;
    const float4* xr4 = (const float4*)(x + (size_t)row * EC);
    const float4* br4 = (const float4*)(bt + (size_t)row * EC);

    __shared__ unsigned hist[256];
    __shared__ unsigned sb[2];

    unsigned prefix = 0;
    unsigned Kp = K;
    for (int pass = 0; pass < 4; ++pass) {
        const int shift = 24 - 8 * pass;
        for (int i = threadIdx.x; i < 256; i += blockDim.x) hist[i] = 0;
        __syncthreads();
        for (int v = threadIdx.x; v < EC / 4; v += blockDim.x) {
            float4 xv = xr4[v];
            float4 bv = br4[v];
            float xs[4] = {xv.x, xv.y, xv.z, xv.w};
            float bs[4] = {bv.x, bv.y, bv.z, bv.w};
            #pragma unroll
            for (int j = 0; j < 4; ++j) {
                float nb, bo;
                compute_vals(xs[j], bs[j], gmax, bp, &nb, &bo);
                unsigned u = map_f(USE_NB ? nb : bo);
                bool match = (pass == 0) || ((u >> (32 - 8 * pass)) == prefix);
                if (match) atomicAdd(&hist[(u >> shift) & 0xFFu], 1u);
            }
        }
        __syncthreads();
        if (threadIdx.x == 0) {
            unsigned cum = 0, bsel = 0, krem = Kp;
            for (int b = 255; b >= 0; --b) {
                unsigned h = hist[b];
                if (cum + h >= Kp) { bsel = (unsigned)b; krem = Kp - cum; break; }
                cum += h;
            }
            sb[0] = (prefix << 8) | bsel;
            sb[1] = krem;
        }
        __syncthreads();
        prefix = sb[0];
        Kp = sb[1];
        __syncthreads();
    }
    unsigned u_t = prefix;
    unsigned ties = Kp;  // >= 1 by construction

    // Ordered scan: index of the ties-th element equal to u_t (stable-sort tie cutoff)
    __shared__ unsigned s_wcnt[16];
    __shared__ unsigned s_run;
    __shared__ int s_cut;
    if (threadIdx.x == 0) { s_run = 0; s_cut = -1; }
    __syncthreads();
    int nw = (int)blockDim.x >> 6;
    int wid = threadIdx.x >> 6, lane = threadIdx.x & 63;
    const float* xs = x + (size_t)row * EC;
    const float* bs = bt + (size_t)row * EC;
    for (int base0 = 0; base0 < EC; base0 += blockDim.x) {
        int i = base0 + threadIdx.x;
        bool eq = false;
        if (i < EC) {
            float nb, bo;
            compute_vals(xs[i], bs[i], gmax, bp, &nb, &bo);
            eq = (map_f(USE_NB ? nb : bo) == u_t);
        }
        unsigned long long bal = __ballot(eq);
        if (lane == 0) s_wcnt[wid] = (unsigned)__popcll(bal);
        __syncthreads();
        unsigned run = s_run;
        unsigned wpre = 0;
        for (int w = 0; w < wid; ++w) wpre += s_wcnt[w];
        if (eq) {
            unsigned r = run + wpre + (unsigned)__popcll(bal & ((1ull << lane) - 1ull));
            if (r == ties - 1) s_cut = i;
        }
        __syncthreads();
        if (threadIdx.x == 0) {
            unsigned tot = 0;
            for (int w = 0; w < nw; ++w) tot += s_wcnt[w];
            s_run = run + tot;
        }
        __syncthreads();
        if (s_run >= ties) break;
    }
    if (threadIdx.x == 0) {
        int base = USE_NB ? 136 : 8;
        ws[base + row] = u_t;
        ws[base + 64 + row] = (unsigned)s_cut;
    }
}

// ---------------- Kernel C: mark + write both outputs + count active ----------------
__global__ void kmark(const float4* __restrict__ x4, const float4* __restrict__ bt4,
                      const float* __restrict__ bp_p, unsigned* ws,
                      float4* __restrict__ out4, float4* __restrict__ fb4) {
    float gmax = unmap_f(ws[0]);
    float bp = *bp_p;
    unsigned cnt = 0;
    const size_t nvec = (size_t)BR * EC / 4;
    size_t stride = (size_t)gridDim.x * blockDim.x;
    for (size_t v = (size_t)blockIdx.x * blockDim.x + threadIdx.x; v < nvec; v += stride) {
        size_t e0 = v << 2;
        int row = (int)(e0 >> 17);
        int col = (int)(e0 & (size_t)(EC - 1));
        unsigned u_t = ws[8 + row];
        int cut = (int)ws[72 + row];
        float4 xv = x4[v], bv = bt4[v];
        float xarr[4] = {xv.x, xv.y, xv.z, xv.w};
        float barr[4] = {bv.x, bv.y, bv.z, bv.w};
        float o[4], f[4];
        #pragma unroll
        for (int j = 0; j < 4; ++j) {
            float nb, bo;
            compute_vals(xarr[j], barr[j], gmax, bp, &nb, &bo);
            unsigned u = map_f(bo);
            bool sel = (u > u_t) || ((u == u_t) && ((col + j) <= cut));
            bool saved = sel && (u > 0x80000000u);  // boosted > 0
            o[j] = saved ? 1.0f : 0.0f;
            f[j] = saved ? 0.0f : nb;
            cnt += saved ? 1u : 0u;
        }
        out4[v] = make_float4(o[0], o[1], o[2], o[3]);
        fb4[v] = make_float4(f[0], f[1], f[2], f[3]);
    }
    for (int off = 32; off; off >>= 1) cnt += __shfl_down(cnt, off, 64);
    __shared__ unsigned sc;
    if (threadIdx.x == 0) sc = 0;
    __syncthreads();
    if ((threadIdx.x & 63) == 0) atomicAdd(&sc, cnt);
    __syncthreads();
    if (threadIdx.x == 0) atomicAdd(&ws[1], sc);
}

// ---------------- Kernel D: compute need/to_activate flag ----------------
__global__ void kneed(const float* __restrict__ sp, unsigned* ws) {
    if (threadIdx.x == 0 && blockIdx.x == 0) {
        float min_active = floorf(sp[0] * (float)EC);
        float active = (float)ws[1];
        ws[2] = (active < min_active) ? (unsigned)ceilf(min_active - active) : 0u;
    }
}

// ---------------- Kernel E: apply correction (gated; dead for this input) ----------------
__global__ void kfix(const float4* __restrict__ x4, const float4* __restrict__ bt4,
                     const float* __restrict__ bp_p, const unsigned* __restrict__ ws,
                     float* __restrict__ out, float* __restrict__ fb) {
    if (ws[2] == 0) return;
    float gmax = unmap_f(ws[0]);
    float bp = *bp_p;
    const size_t nvec = (size_t)BR * EC / 4;
    size_t stride = (size_t)gridDim.x * blockDim.x;
    for (size_t v = (size_t)blockIdx.x * blockDim.x + threadIdx.x; v < nvec; v += stride) {
        size_t e0 = v << 2;
        int row = (int)(e0 >> 17);
        int col = (int)(e0 & (size_t)(EC - 1));
        unsigned u_t = ws[136 + row];
        int cut = (int)ws[200 + row];
        float4 xv = x4[v], bv = bt4[v];
        float xarr[4] = {xv.x, xv.y, xv.z, xv.w};
        float barr[4] = {bv.x, bv.y, bv.z, bv.w};
        #pragma unroll
        for (int j = 0; j < 4; ++j) {
            float nb, bo;
            compute_vals(xarr[j], barr[j], gmax, bp, &nb, &bo);
            unsigned u = map_f(nb);
            if (u > u_t || (u == u_t && (col + j) <= cut)) {
                out[e0 + j] = 1.0f;
                fb[e0 + j] = 0.0f;
            }
        }
    }
}

extern "C" void kernel_launch(void* const* d_in, const int* in_sizes, int n_in,
                              void* d_out, int out_size, void* d_ws, size_t ws_size,
                              hipStream_t stream) {
    const float* x  = (const float*)d_in[0];
    const float* bt = (const float*)d_in[1];
    const float* sp = (const float*)d_in[2];
    const float* bp = (const float*)d_in[3];
    float* out = (float*)d_out;
    float* fb  = out + (size_t)BR * EC;
    unsigned* ws = (unsigned*)d_ws;

    // zero ws[0] (gmax), ws[1] (active), ws[2] (to_activate) + slack
    hipMemsetAsync(d_ws, 0, 4096, stream);

    kmax<<<2048, 256, 0, stream>>>((const float4*)x, ws, BR * EC / 4);
    kselect<0><<<BR, 1024, 0, stream>>>(x, bt, sp, bp, ws);
    kmark<<<2048, 256, 0, stream>>>((const float4*)x, (const float4*)bt, bp, ws,
                                    (float4*)out, (float4*)fb);
    kneed<<<1, 64, 0, stream>>>(sp, ws);
    kselect<1><<<BR, 1024, 0, stream>>>(x, bt, sp, bp, ws);
    kfix<<<2048, 256, 0, stream>>>((const float4*)x, (const float4*)bt, bp, ws, out, fb);
}